// Round 12
// baseline (577.845 us; speedup 1.0000x reference)
//
#include <hip/hip_runtime.h>
#include <math.h>

#define NN 100000
#define NE 1600000
#define H 128
#define LH 384
#define GG 512
#define CC 10
#define EPSBN 1e-5f
#define BSH 9  // bucket shift: 512 nodes per bucket

typedef __attribute__((ext_vector_type(4))) float f32x4;
typedef __attribute__((ext_vector_type(2))) float f32x2;
typedef __attribute__((ext_vector_type(8))) short s16x8;
typedef __attribute__((ext_vector_type(4))) uint u32x4;
typedef unsigned long long u64;

__device__ inline ushort f2b(float f) {
    uint u = __float_as_uint(f);
    uint r = (u + 0x7FFFu + ((u >> 16) & 1u)) >> 16;
    return (ushort)r;
}
__device__ inline float b2f(ushort b) { return __uint_as_float(((uint)b) << 16); }
__device__ inline float blo(uint v) { return __uint_as_float(v << 16); }
__device__ inline float bhi(uint v) { return __uint_as_float(v & 0xFFFF0000u); }

// ---------------- W transpose + bf16 convert: WT[j*128+k] = W[k*128+j] ------

__global__ void k_wt(const float* __restrict__ W, ushort* __restrict__ WT, int nmat) {
    int mat = blockIdx.x >> 7;
    int k = blockIdx.x & 127;
    int j = threadIdx.x;  // 128 threads
    WT[(size_t)mat * H * H + j * H + k] = f2b(W[(size_t)mat * H * H + k * H + j]);
}

// ---------------- bucketed CSR build ----------------

__global__ void k_bhist(const int* __restrict__ dst, int* __restrict__ bhist,
                        int e, int nbuck) {
    __shared__ int lh[256];
    lh[threadIdx.x] = 0;
    __syncthreads();
    int stride = gridDim.x * 256;
    for (int i = blockIdx.x * 256 + threadIdx.x; i < e; i += stride)
        atomicAdd(&lh[dst[i] >> BSH], 1);
    __syncthreads();
    int v = lh[threadIdx.x];
    if (threadIdx.x < nbuck && v) atomicAdd(&bhist[threadIdx.x], v);
}

__global__ void k_bscan(const int* __restrict__ bhist, int* __restrict__ bbase,
                        int* __restrict__ bcursor, int nbuck) {
    __shared__ int sh[256];
    int t = threadIdx.x;
    int v = (t < nbuck) ? bhist[t] : 0;
    sh[t] = v;
    __syncthreads();
    for (int off = 1; off < 256; off <<= 1) {
        int x = (t >= off) ? sh[t - off] : 0;
        __syncthreads();
        sh[t] += x;
        __syncthreads();
    }
    int run = sh[t] - v;
    if (t < nbuck) { bbase[t] = run; bcursor[t] = run; }
    if (t == nbuck) bbase[t] = run;
    if (t == 255 && nbuck > 255) bbase[nbuck] = sh[255];
}

// block-aggregated scatter: LDS histogram -> 1 global atomic per (block,bucket)
// packed u32 record: (dst & 511) << 17 | src
__global__ void k_bin(const int* __restrict__ src, const int* __restrict__ dst,
                      int* __restrict__ bcursor, uint* __restrict__ ebuf, int e) {
    __shared__ int lh[256], gb[256], lcur[256];
    int t = threadIdx.x;
    int base = blockIdx.x * 4096;
    int lim = e - base; if (lim > 4096) lim = 4096;
    lh[t] = 0;
    __syncthreads();
    for (int i = t; i < lim; i += 256)
        atomicAdd(&lh[dst[base + i] >> BSH], 1);
    __syncthreads();
    int c = lh[t];
    if (c) gb[t] = atomicAdd(&bcursor[t], c);
    lcur[t] = 0;
    __syncthreads();
    for (int i = t; i < lim; i += 256) {
        int s = src[base + i], d = dst[base + i];
        int b = d >> BSH;
        int p = atomicAdd(&lcur[b], 1);
        ebuf[(size_t)gb[b] + p] = ((uint)(d & 511) << 17) | (uint)s;
    }
}

__global__ void k_bfinal(const uint* __restrict__ ebuf, const int* __restrict__ bbase,
                         int* __restrict__ rp, float* __restrict__ dinv,
                         int* __restrict__ col, int n, int e) {
    __shared__ int hcnt[512], hoff[512], hcur[512];
    int b = blockIdx.x, t = threadIdx.x;
    int node0 = b << BSH;
    int e0 = bbase[b], e1 = bbase[b + 1];
    int m = e1 - e0;
    for (int j = t; j < 512; j += 256) hcnt[j] = 0;
    __syncthreads();
    for (int i = t; i < m; i += 256)
        atomicAdd(&hcnt[ebuf[e0 + i] >> 17], 1);
    __syncthreads();
    if (t == 0) {
        int run = 0;
        for (int j = 0; j < 512; ++j) { hoff[j] = run; run += hcnt[j]; }
    }
    __syncthreads();
    for (int j = t; j < 512; j += 256) {
        int node = node0 + j;
        if (node < n) {
            rp[node] = e0 + hoff[j];
            dinv[node] = rsqrtf((float)(hcnt[j] + 1));
        }
        hcur[j] = hoff[j];
    }
    if (b == 0 && t == 0) rp[n] = e;
    __syncthreads();
    for (int i = t; i < m; i += 256) {
        uint u = ebuf[e0 + i];
        int p = atomicAdd(&hcur[u >> 17], 1);
        col[e0 + p] = (int)(u & 0x1FFFFu);
    }
}

// ---------------- edge records: u32 = dinv[src] top-15 bits | src (17 bits) --

__global__ void k_erec(const int* __restrict__ col, const float* __restrict__ dinv,
                       uint* __restrict__ erec, int e) {
    int i = blockIdx.x * 256 + threadIdx.x;
    if (i < e) {
        int s = col[i];
        uint db = __float_as_uint(dinv[s]);
        erec[i] = ((db + 0x10000u) & 0xFFFE0000u) | (uint)s;  // round-to-nearest 15-bit
    }
}

// ---------------- MFMA GEMM: C = BNReLU(A)[n,128] @ W, half-planar out ------
// MODE 0: A fp32 raw (layer 0). MODE 1: A bf16 + fused BN+ReLU (layers 1,2).
// Output hwh: half h of row r at hwh[(h*NN + r)*64 + (col&63)]  (128 B lines).

template <int MODE>
__global__ __launch_bounds__(256) void k_gemm(
    const void* __restrict__ Ap, const ushort* __restrict__ WT,
    const float* __restrict__ stats, const float* __restrict__ g,
    const float* __restrict__ bt, float inv_n,
    ushort* __restrict__ Cout, int n) {
    __shared__ ushort As[64][136];
    __shared__ ushort Ws[128][136];
    __shared__ float bsc[128], bshf[128];
    int t = threadIdx.x;
    int wave = t >> 6, lane = t & 63;
    int rowBase = blockIdx.x * 64;

    if (MODE == 1) {
        if (t < 128) {
            float mu = stats[t] * inv_n;
            float var = stats[128 + t] * inv_n - mu * mu;
            float sc = g[t] * rsqrtf(var + EPSBN);
            bsc[t] = sc;
            bshf[t] = bt[t] - mu * sc;
        }
        __syncthreads();
    }

    if (MODE == 0) {
        const float* A = (const float*)Ap;
        for (int i = t; i < 64 * 32; i += 256) {
            int r = i >> 5, c4 = i & 31;
            int row = rowBase + r;
            float4 v = make_float4(0.f, 0.f, 0.f, 0.f);
            if (row < n) v = *(const float4*)(A + (size_t)row * H + c4 * 4);
            ushort4 o;
            o.x = f2b(v.x); o.y = f2b(v.y); o.z = f2b(v.z); o.w = f2b(v.w);
            *(ushort4*)(&As[r][c4 * 4]) = o;
        }
    } else {
        const ushort* A = (const ushort*)Ap;
        for (int i = t; i < 64 * 16; i += 256) {
            int r = i >> 4, c8 = i & 15;
            int row = rowBase + r;
            uint4 v = make_uint4(0u, 0u, 0u, 0u);
            if (row < n) v = *(const uint4*)(A + (size_t)row * H + c8 * 8);
            const uint* pv = (const uint*)&v;
            ushort o[8];
#pragma unroll
            for (int j = 0; j < 4; ++j) {
                int f0 = c8 * 8 + 2 * j;
                float v0 = fmaxf(fmaf(blo(pv[j]), bsc[f0], bshf[f0]), 0.f);
                float v1 = fmaxf(fmaf(bhi(pv[j]), bsc[f0 + 1], bshf[f0 + 1]), 0.f);
                o[2 * j] = f2b(v0);
                o[2 * j + 1] = f2b(v1);
            }
            *(uint4*)(&As[r][c8 * 8]) = *(const uint4*)o;
        }
    }
    for (int i = t; i < 128 * 16; i += 256) {
        int j = i >> 4, c8 = i & 15;
        uint4 v = *(const uint4*)(WT + j * H + c8 * 8);
        *(uint4*)(&Ws[j][c8 * 8]) = v;
    }
    __syncthreads();

    int m = lane & 15, qd = lane >> 4;
    f32x4 acc[8];
#pragma unroll
    for (int c = 0; c < 8; ++c) acc[c] = (f32x4){0.f, 0.f, 0.f, 0.f};
#pragma unroll
    for (int kc = 0; kc < 4; ++kc) {
        int kof = kc * 32 + qd * 8;
        s16x8 afrag = *(const s16x8*)(&As[wave * 16 + m][kof]);
#pragma unroll
        for (int c = 0; c < 8; ++c) {
            s16x8 bfrag = *(const s16x8*)(&Ws[c * 16 + m][kof]);
            acc[c] = __builtin_amdgcn_mfma_f32_16x16x32_bf16(afrag, bfrag, acc[c], 0, 0, 0);
        }
    }
#pragma unroll
    for (int c = 0; c < 8; ++c) {
        int colI = c * 16 + m;
        int hh = colI >> 6, cq = colI & 63;
#pragma unroll
        for (int r = 0; r < 4; ++r) {
            int row = rowBase + wave * 16 + qd * 4 + r;
            if (row < n)
                __builtin_nontemporal_store(
                    f2b(acc[c][r]), &Cout[((size_t)hh * NN + row) * 64 + cq]);
        }
    }
}

// ---------------- Aggregation + fused BN stats (half-split, per-sub nodes) --
// 8-lane subgroup <-> 128 B half-row; dynamic node ownership via LDS cursor;
// 128-node groups x2 halves -> 1564 blocks (~6/CU) for occupancy.

__global__ __launch_bounds__(256) void k_agg(
    const ushort* __restrict__ hwh, const int* __restrict__ rp,
    const uint* __restrict__ erec, const float* __restrict__ dinv,
    float* __restrict__ stats, ushort* __restrict__ aggb, int n) {
    __shared__ int cursor;
    __shared__ float lsum[64], lsq[64];
    int t = threadIdx.x;
    int lane = t & 63;
    int sl = lane & 7;       // lane within 8-lane sub
    int sub0 = lane & ~7;    // first lane of sub
    int half = blockIdx.x & 1;
    int nodeBase = (blockIdx.x >> 1) * 128;
    if (t == 0) cursor = 0;
    if (t < 64) { lsum[t] = 0.f; lsq[t] = 0.f; }
    __syncthreads();
    const uint4* hw4 = (const uint4*)hwh;  // half-planar: (half*NN + node)*8 + sl
    u32x4* agg4 = (u32x4*)aggb;            // interleaved: node*16 + half*8 + sl
    f32x2 ss[4], sq[4];
#pragma unroll
    for (int j = 0; j < 4; ++j) { ss[j] = (f32x2){0.f, 0.f}; sq[j] = (f32x2){0.f, 0.f}; }

    for (;;) {
        int ni = 0;
        if (sl == 0) ni = atomicAdd(&cursor, 1);
        ni = __shfl(ni, sub0);
        int node = nodeBase + ni;
        if (ni >= 128 || node >= n) break;
        float dn = dinv[node];
        f32x2 acc[4];
        {
            uint4 v = hw4[((size_t)half * NN + node) * 8 + sl];
            const uint* pv = (const uint*)&v;
#pragma unroll
            for (int j = 0; j < 4; ++j)
                acc[j] = (f32x2){dn * blo(pv[j]), dn * bhi(pv[j])};
        }
        int p = rp[node], pe = rp[node + 1];
        for (; p < pe; p += 4) {
            int i1 = p + 1 < pe ? p + 1 : pe - 1;
            int i2 = p + 2 < pe ? p + 2 : pe - 1;
            int i3 = p + 3 < pe ? p + 3 : pe - 1;
            uint r0 = erec[p], r1 = erec[i1], r2 = erec[i2], r3 = erec[i3];
            float w0 = __uint_as_float(r0 & 0xFFFE0000u);
            float w1 = (p + 1 < pe) ? __uint_as_float(r1 & 0xFFFE0000u) : 0.f;
            float w2 = (p + 2 < pe) ? __uint_as_float(r2 & 0xFFFE0000u) : 0.f;
            float w3 = (p + 3 < pe) ? __uint_as_float(r3 & 0xFFFE0000u) : 0.f;
            uint4 v0 = hw4[((size_t)half * NN + (r0 & 0x1FFFFu)) * 8 + sl];
            uint4 v1 = hw4[((size_t)half * NN + (r1 & 0x1FFFFu)) * 8 + sl];
            uint4 v2 = hw4[((size_t)half * NN + (r2 & 0x1FFFFu)) * 8 + sl];
            uint4 v3 = hw4[((size_t)half * NN + (r3 & 0x1FFFFu)) * 8 + sl];
            const uint* p0 = (const uint*)&v0;
            const uint* p1 = (const uint*)&v1;
            const uint* p2 = (const uint*)&v2;
            const uint* p3 = (const uint*)&v3;
            f32x2 wv0 = (f32x2){w0, w0}, wv1 = (f32x2){w1, w1};
            f32x2 wv2 = (f32x2){w2, w2}, wv3 = (f32x2){w3, w3};
#pragma unroll
            for (int j = 0; j < 4; ++j) {
                acc[j] = __builtin_elementwise_fma(wv0, (f32x2){blo(p0[j]), bhi(p0[j])}, acc[j]);
                acc[j] = __builtin_elementwise_fma(wv1, (f32x2){blo(p1[j]), bhi(p1[j])}, acc[j]);
                acc[j] = __builtin_elementwise_fma(wv2, (f32x2){blo(p2[j]), bhi(p2[j])}, acc[j]);
                acc[j] = __builtin_elementwise_fma(wv3, (f32x2){blo(p3[j]), bhi(p3[j])}, acc[j]);
            }
        }
        u32x4 o;
        f32x2 dn2 = (f32x2){dn, dn};
#pragma unroll
        for (int j = 0; j < 4; ++j) {
            f32x2 ov = dn2 * acc[j];
            ss[j] += ov;
            sq[j] = __builtin_elementwise_fma(ov, ov, sq[j]);
            o[j] = (uint)f2b(ov.x) | ((uint)f2b(ov.y) << 16);
        }
        __builtin_nontemporal_store(o, &agg4[(size_t)node * 16 + half * 8 + sl]);
    }
#pragma unroll
    for (int j = 0; j < 4; ++j) {
        atomicAdd(&lsum[sl * 8 + 2 * j], ss[j].x);
        atomicAdd(&lsum[sl * 8 + 2 * j + 1], ss[j].y);
        atomicAdd(&lsq[sl * 8 + 2 * j], sq[j].x);
        atomicAdd(&lsq[sl * 8 + 2 * j + 1], sq[j].y);
    }
    __syncthreads();
    if (t < 64) {
        atomicAdd(&stats[half * 64 + t], lsum[t]);
        atomicAdd(&stats[128 + half * 64 + t], lsq[t]);
    }
}

// ---------------- Pooling (BN+ReLU inline, vectorized) ----------------

__global__ void k_gbound(const int* __restrict__ batch, int* __restrict__ gptr, int n) {
    int g = blockIdx.x * 256 + threadIdx.x;
    if (g > GG) return;
    int lo = 0, hi = n;
    while (lo < hi) {
        int mid = (lo + hi) >> 1;
        if (batch[mid] < g) lo = mid + 1; else hi = mid;
    }
    gptr[g] = lo;
}

__global__ __launch_bounds__(256) void k_pool(
    const ushort* __restrict__ aggall, const float* __restrict__ statsall,
    const float* __restrict__ g1, const float* __restrict__ bt1,
    const float* __restrict__ gc, const float* __restrict__ btc,
    const int* __restrict__ gptr, float* __restrict__ pooled, float inv_n) {
    __shared__ float bsc[64], bshf[64];
    __shared__ float red[32][64];
    int g = blockIdx.x;
    int s = blockIdx.y;              // feature slice: 64 feats
    int sec = s >> 1;                // section (layer) 0..2
    int c = threadIdx.x & 7;         // uint4 chunk within slice
    int rg = threadIdx.x >> 3;       // row lane 0..31
    int t = threadIdx.x;

    if (t < 64) {
        int feat = (s & 1) * 64 + t;  // feature within section (0..127)
        const float* st = statsall + sec * 256;
        float mu = st[feat] * inv_n;
        float var = st[128 + feat] * inv_n - mu * mu;
        float gm = (sec == 0) ? g1[feat] : gc[(sec - 1) * H + feat];
        float bm = (sec == 0) ? bt1[feat] : btc[(sec - 1) * H + feat];
        float sc = gm * rsqrtf(var + EPSBN);
        bsc[t] = sc;
        bshf[t] = bm - mu * sc;
    }
    __syncthreads();

    int r0 = gptr[g], r1 = gptr[g + 1];
    const uint4* a4 = (const uint4*)aggall;
    size_t secBase = (size_t)sec * NN * 16;
    int cOff = (s & 1) * 8 + c;
    float acc[8];
#pragma unroll
    for (int j = 0; j < 8; ++j) acc[j] = 0.f;
    for (int r = r0 + rg; r < r1; r += 32) {
        uint4 v = a4[secBase + (size_t)r * 16 + cOff];
        const uint* pv = (const uint*)&v;
#pragma unroll
        for (int j = 0; j < 4; ++j) {
            int f0 = c * 8 + 2 * j;
            acc[2 * j]     += fmaxf(fmaf(blo(pv[j]), bsc[f0], bshf[f0]), 0.f);
            acc[2 * j + 1] += fmaxf(fmaf(bhi(pv[j]), bsc[f0 + 1], bshf[f0 + 1]), 0.f);
        }
    }
#pragma unroll
    for (int j = 0; j < 8; ++j) red[rg][c * 8 + j] = acc[j];
    __syncthreads();
    if (t < 64) {
        float sum = 0.f;
#pragma unroll
        for (int rr = 0; rr < 32; ++rr) sum += red[rr][t];
        float cnt = (float)(r1 - r0);
        pooled[g * LH + s * 64 + t] = sum / fmaxf(cnt, 1.f);
    }
}

// ---------------- MLP head ----------------

__global__ void k_mlp1(const float* __restrict__ pooled, const float* __restrict__ Wl1,
                       const float* __restrict__ bl1, float* __restrict__ z) {
    __shared__ float row[LH];
    int g = blockIdx.x;
    int j = threadIdx.x;  // 128 threads
    for (int k = j; k < LH; k += H) row[k] = pooled[g * LH + k];
    __syncthreads();
    float acc = bl1[j];
    for (int k = 0; k < LH; ++k) acc += row[k] * Wl1[k * H + j];
    z[g * H + j] = acc;
}

__global__ void k_zstats(const float* __restrict__ z, float* __restrict__ st) {
    int j = threadIdx.x;  // 128 threads, 1 block
    float s = 0.f, q = 0.f;
    for (int g = 0; g < GG; ++g) {
        float v = z[g * H + j];
        s += v;
        q += v * v;
    }
    st[j] = s;
    st[128 + j] = q;
}

__global__ void k_mlp2(const float* __restrict__ z, const float* __restrict__ st,
                       const float* __restrict__ gl, const float* __restrict__ btl,
                       const float* __restrict__ Wl2, const float* __restrict__ bl2,
                       float* __restrict__ out) {
    __shared__ float zn[H];
    __shared__ float logit[CC];
    int g = blockIdx.x;
    int t = threadIdx.x;  // 128 threads
    float mu = st[t] * (1.f / GG);
    float var = st[128 + t] * (1.f / GG) - mu * mu;
    float v = (z[g * H + t] - mu) * rsqrtf(var + EPSBN) * gl[t] + btl[t];
    zn[t] = fmaxf(v, 0.f);
    __syncthreads();
    if (t < CC) {
        float acc = bl2[t];
        for (int k = 0; k < H; ++k) acc += zn[k] * Wl2[k * CC + t];
        logit[t] = acc;
    }
    __syncthreads();
    if (t == 0) {
        float m = -1e30f;
        for (int c = 0; c < CC; ++c) m = fmaxf(m, logit[c]);
        float se = 0.f;
        for (int c = 0; c < CC; ++c) se += expf(logit[c] - m);
        float lse = m + logf(se);
        for (int c = 0; c < CC; ++c) out[g * CC + c] = logit[c] - lse;
    }
}

// ---------------- launch ----------------

extern "C" void kernel_launch(void* const* d_in, const int* in_sizes, int n_in,
                              void* d_out, int out_size, void* d_ws, size_t ws_size,
                              hipStream_t stream) {
    const float* x   = (const float*)d_in[0];
    const int*   ei  = (const int*)d_in[1];
    const int*   bat = (const int*)d_in[2];
    const float* W1  = (const float*)d_in[3];
    const float* g1  = (const float*)d_in[5];
    const float* bt1 = (const float*)d_in[6];
    const float* Wc  = (const float*)d_in[7];
    const float* gc  = (const float*)d_in[9];
    const float* btc = (const float*)d_in[10];
    const float* Wl1 = (const float*)d_in[11];
    const float* bl1 = (const float*)d_in[12];
    const float* gl  = (const float*)d_in[13];
    const float* btl = (const float*)d_in[14];
    const float* Wl2 = (const float*)d_in[15];
    const float* bl2 = (const float*)d_in[16];
    float* out = (float*)d_out;

    const int n = in_sizes[2];
    const int e = in_sizes[1] / 2;
    const int* src = ei;
    const int* dst = ei + e;
    const int nbuck = (n + 511) / 512;  // <= 256
    const float inv_n = 1.0f / (float)n;

    size_t off = 0;
    char* base = (char*)d_ws;
    auto take = [&](size_t nbytes) -> void* {
        void* p = base + off;
        off += (nbytes + 255) & ~(size_t)255;
        return p;
    };
    int*    rp      = (int*)take((size_t)(NN + 1) * 4);
    int*    col     = (int*)take((size_t)NE * 4);
    float*  dinv    = (float*)take((size_t)NN * 4);
    int*    bhist   = (int*)take(1024 + 8);
    int*    bbase   = (int*)take(1024 + 8);
    int*    bcursor = (int*)take(1024 + 8);
    uint*   ebuf    = (uint*)take((size_t)NE * 4);
    uint*   erec    = (uint*)take((size_t)NE * 4);
    float*  stats   = (float*)take(3 * 1024);
    int*    gptr    = (int*)take((size_t)(GG + 1) * 4);
    ushort* WTb     = (ushort*)take((size_t)3 * H * H * 2);
    ushort* hwb     = (ushort*)take((size_t)NN * H * 2);
    ushort* aggb    = (ushort*)take((size_t)3 * NN * H * 2);
    float*  pooled  = (float*)take((size_t)GG * LH * 4);
    float*  z       = (float*)take((size_t)GG * H * 4);
    float*  zst     = (float*)take(1024);

    // ---- weight transpose/convert ----
    k_wt<<<H, H, 0, stream>>>(W1, WTb, 1);
    k_wt<<<2 * H, H, 0, stream>>>(Wc, WTb + (size_t)H * H, 2);

    // ---- bucketed CSR build ----
    hipMemsetAsync(bhist, 0, 1024 + 8, stream);
    k_bhist<<<256, 256, 0, stream>>>(dst, bhist, e, nbuck);
    k_bscan<<<1, 256, 0, stream>>>(bhist, bbase, bcursor, nbuck);
    k_bin<<<(e + 4095) / 4096, 256, 0, stream>>>(src, dst, bcursor, ebuf, e);
    k_bfinal<<<nbuck, 256, 0, stream>>>(ebuf, bbase, rp, dinv, col, n, e);
    k_erec<<<(e + 255) / 256, 256, 0, stream>>>(col, dinv, erec, e);

    // ---- 3 GCN layers (BN+ReLU of layer l-1 fused into layer l's GEMM) ----
    hipMemsetAsync(stats, 0, 3 * 1024, stream);
    for (int l = 0; l < 3; ++l) {
        const ushort* WT = WTb + (size_t)l * H * H;

        if (l == 0) {
            k_gemm<0><<<(n + 63) / 64, 256, 0, stream>>>(
                x, WT, nullptr, nullptr, nullptr, inv_n, hwb, n);
        } else {
            const float* gm  = (l == 1) ? g1 : gc;
            const float* btm = (l == 1) ? bt1 : btc;
            k_gemm<1><<<(n + 63) / 64, 256, 0, stream>>>(
                aggb + (size_t)(l - 1) * NN * H, WT, stats + (size_t)(l - 1) * 256,
                gm, btm, inv_n, hwb, n);
        }
        k_agg<<<((n + 127) / 128) * 2, 256, 0, stream>>>(
            hwb, rp, erec, dinv, stats + (size_t)l * 256, aggb + (size_t)l * NN * H, n);
    }

    // ---- pooling ----
    k_gbound<<<3, 256, 0, stream>>>(bat, gptr, n);
    {
        dim3 pg(GG, 6);
        k_pool<<<pg, 256, 0, stream>>>(aggb, stats, g1, bt1, gc, btc, gptr, pooled, inv_n);
    }

    // ---- MLP head ----
    k_mlp1<<<GG, H, 0, stream>>>(pooled, Wl1, bl1, z);
    k_zstats<<<1, H, 0, stream>>>(z, zst);
    k_mlp2<<<GG, H, 0, stream>>>(z, zst, gl, btl, Wl2, bl2, out);
}

// Round 13
// 527.789 us; speedup vs baseline: 1.0948x; 1.0948x over previous
//
#include <hip/hip_runtime.h>
#include <math.h>

#define NN 100000
#define NE 1600000
#define H 128
#define LH 384
#define GG 512
#define CC 10
#define EPSBN 1e-5f
#define BSH 9  // bucket shift: 512 nodes per bucket

typedef __attribute__((ext_vector_type(4))) float f32x4;
typedef __attribute__((ext_vector_type(2))) float f32x2;
typedef __attribute__((ext_vector_type(8))) short s16x8;
typedef unsigned long long u64;

__device__ inline ushort f2b(float f) {
    uint u = __float_as_uint(f);
    uint r = (u + 0x7FFFu + ((u >> 16) & 1u)) >> 16;
    return (ushort)r;
}
__device__ inline float b2f(ushort b) { return __uint_as_float(((uint)b) << 16); }
__device__ inline float blo(uint v) { return __uint_as_float(v << 16); }
__device__ inline float bhi(uint v) { return __uint_as_float(v & 0xFFFF0000u); }

// ---------------- W transpose + bf16 convert: WT[j*128+k] = W[k*128+j] ------

__global__ void k_wt(const float* __restrict__ W, ushort* __restrict__ WT, int nmat) {
    int mat = blockIdx.x >> 7;
    int k = blockIdx.x & 127;
    int j = threadIdx.x;  // 128 threads
    WT[(size_t)mat * H * H + j * H + k] = f2b(W[(size_t)mat * H * H + k * H + j]);
}

// ---------------- bucketed CSR build ----------------

__global__ void k_bhist(const int* __restrict__ dst, int* __restrict__ bhist,
                        int e, int nbuck) {
    __shared__ int lh[256];
    lh[threadIdx.x] = 0;
    __syncthreads();
    int stride = gridDim.x * 256;
    for (int i = blockIdx.x * 256 + threadIdx.x; i < e; i += stride)
        atomicAdd(&lh[dst[i] >> BSH], 1);
    __syncthreads();
    int v = lh[threadIdx.x];
    if (threadIdx.x < nbuck && v) atomicAdd(&bhist[threadIdx.x], v);
}

__global__ void k_bscan(const int* __restrict__ bhist, int* __restrict__ bbase,
                        int* __restrict__ bcursor, int nbuck) {
    __shared__ int sh[256];
    int t = threadIdx.x;
    int v = (t < nbuck) ? bhist[t] : 0;
    sh[t] = v;
    __syncthreads();
    for (int off = 1; off < 256; off <<= 1) {
        int x = (t >= off) ? sh[t - off] : 0;
        __syncthreads();
        sh[t] += x;
        __syncthreads();
    }
    int run = sh[t] - v;
    if (t < nbuck) { bbase[t] = run; bcursor[t] = run; }
    if (t == nbuck) bbase[t] = run;
    if (t == 255 && nbuck > 255) bbase[nbuck] = sh[255];
}

// block-aggregated scatter: LDS histogram -> 1 global atomic per (block,bucket)
// packed u32 record: (dst & 511) << 17 | src
__global__ void k_bin(const int* __restrict__ src, const int* __restrict__ dst,
                      int* __restrict__ bcursor, uint* __restrict__ ebuf, int e) {
    __shared__ int lh[256], gb[256], lcur[256];
    int t = threadIdx.x;
    int base = blockIdx.x * 4096;
    int lim = e - base; if (lim > 4096) lim = 4096;
    lh[t] = 0;
    __syncthreads();
    for (int i = t; i < lim; i += 256)
        atomicAdd(&lh[dst[base + i] >> BSH], 1);
    __syncthreads();
    int c = lh[t];
    if (c) gb[t] = atomicAdd(&bcursor[t], c);
    lcur[t] = 0;
    __syncthreads();
    for (int i = t; i < lim; i += 256) {
        int s = src[base + i], d = dst[base + i];
        int b = d >> BSH;
        int p = atomicAdd(&lcur[b], 1);
        ebuf[(size_t)gb[b] + p] = ((uint)(d & 511) << 17) | (uint)s;
    }
}

// phase A: per-node histogram -> rp, dinv
__global__ void k_bfinalA(const uint* __restrict__ ebuf, const int* __restrict__ bbase,
                          int* __restrict__ rp, float* __restrict__ dinv, int n, int e) {
    __shared__ int hcnt[512], hoff[512];
    int b = blockIdx.x, t = threadIdx.x;
    int node0 = b << BSH;
    int e0 = bbase[b], e1 = bbase[b + 1];
    int m = e1 - e0;
    for (int j = t; j < 512; j += 256) hcnt[j] = 0;
    __syncthreads();
    for (int i = t; i < m; i += 256)
        atomicAdd(&hcnt[ebuf[e0 + i] >> 17], 1);
    __syncthreads();
    if (t == 0) {
        int run = 0;
        for (int j = 0; j < 512; ++j) { hoff[j] = run; run += hcnt[j]; }
    }
    __syncthreads();
    for (int j = t; j < 512; j += 256) {
        int node = node0 + j;
        if (node < n) {
            rp[node] = e0 + hoff[j];
            dinv[node] = rsqrtf((float)(hcnt[j] + 1));
        }
    }
    if (b == 0 && t == 0) rp[n] = e;
}

// phase B: scatter edges into CSR order, writing packed (dinv[src], src) records
__global__ void k_bfinalB(const uint* __restrict__ ebuf, const int* __restrict__ bbase,
                          const int* __restrict__ rp, const float* __restrict__ dinv,
                          uint* __restrict__ erec, int n) {
    __shared__ int hcur[512];
    int b = blockIdx.x, t = threadIdx.x;
    int node0 = b << BSH;
    int e0 = bbase[b], e1 = bbase[b + 1];
    int m = e1 - e0;
    for (int j = t; j < 512; j += 256) {
        int node = node0 + j;
        hcur[j] = (node < n) ? rp[node] - e0 : 0;
    }
    __syncthreads();
    for (int i = t; i < m; i += 256) {
        uint u = ebuf[e0 + i];
        int s = (int)(u & 0x1FFFFu);
        int p = atomicAdd(&hcur[u >> 17], 1);
        uint db = __float_as_uint(dinv[s]);
        erec[e0 + p] = ((db + 0x10000u) & 0xFFFE0000u) | (uint)s;  // 15-bit dinv | 17-bit src
    }
}

// ---------------- MFMA GEMM: C = BNReLU(A)[n,128] @ W, half-planar out ------
// MODE 0: A fp32 raw (layer 0). MODE 1: A bf16 + fused BN+ReLU (layers 1,2).
// Output hwh: half h of row r at hwh[(h*NN + r)*64 + (col&63)]  (128 B lines).

template <int MODE>
__global__ __launch_bounds__(256) void k_gemm(
    const void* __restrict__ Ap, const ushort* __restrict__ WT,
    const float* __restrict__ stats, const float* __restrict__ g,
    const float* __restrict__ bt, float inv_n,
    ushort* __restrict__ Cout, int n) {
    __shared__ ushort As[64][136];
    __shared__ ushort Ws[128][136];
    __shared__ float bsc[128], bshf[128];
    int t = threadIdx.x;
    int wave = t >> 6, lane = t & 63;
    int rowBase = blockIdx.x * 64;

    if (MODE == 1) {
        if (t < 128) {
            float mu = stats[t] * inv_n;
            float var = stats[128 + t] * inv_n - mu * mu;
            float sc = g[t] * rsqrtf(var + EPSBN);
            bsc[t] = sc;
            bshf[t] = bt[t] - mu * sc;
        }
        __syncthreads();
    }

    if (MODE == 0) {
        const float* A = (const float*)Ap;
        for (int i = t; i < 64 * 32; i += 256) {
            int r = i >> 5, c4 = i & 31;
            int row = rowBase + r;
            float4 v = make_float4(0.f, 0.f, 0.f, 0.f);
            if (row < n) v = *(const float4*)(A + (size_t)row * H + c4 * 4);
            ushort4 o;
            o.x = f2b(v.x); o.y = f2b(v.y); o.z = f2b(v.z); o.w = f2b(v.w);
            *(ushort4*)(&As[r][c4 * 4]) = o;
        }
    } else {
        const ushort* A = (const ushort*)Ap;
        for (int i = t; i < 64 * 16; i += 256) {
            int r = i >> 4, c8 = i & 15;
            int row = rowBase + r;
            uint4 v = make_uint4(0u, 0u, 0u, 0u);
            if (row < n) v = *(const uint4*)(A + (size_t)row * H + c8 * 8);
            const uint* pv = (const uint*)&v;
            ushort o[8];
#pragma unroll
            for (int j = 0; j < 4; ++j) {
                int f0 = c8 * 8 + 2 * j;
                float v0 = fmaxf(fmaf(blo(pv[j]), bsc[f0], bshf[f0]), 0.f);
                float v1 = fmaxf(fmaf(bhi(pv[j]), bsc[f0 + 1], bshf[f0 + 1]), 0.f);
                o[2 * j] = f2b(v0);
                o[2 * j + 1] = f2b(v1);
            }
            *(uint4*)(&As[r][c8 * 8]) = *(const uint4*)o;
        }
    }
    for (int i = t; i < 128 * 16; i += 256) {
        int j = i >> 4, c8 = i & 15;
        uint4 v = *(const uint4*)(WT + j * H + c8 * 8);
        *(uint4*)(&Ws[j][c8 * 8]) = v;
    }
    __syncthreads();

    int m = lane & 15, qd = lane >> 4;
    f32x4 acc[8];
#pragma unroll
    for (int c = 0; c < 8; ++c) acc[c] = (f32x4){0.f, 0.f, 0.f, 0.f};
#pragma unroll
    for (int kc = 0; kc < 4; ++kc) {
        int kof = kc * 32 + qd * 8;
        s16x8 afrag = *(const s16x8*)(&As[wave * 16 + m][kof]);
#pragma unroll
        for (int c = 0; c < 8; ++c) {
            s16x8 bfrag = *(const s16x8*)(&Ws[c * 16 + m][kof]);
            acc[c] = __builtin_amdgcn_mfma_f32_16x16x32_bf16(afrag, bfrag, acc[c], 0, 0, 0);
        }
    }
#pragma unroll
    for (int c = 0; c < 8; ++c) {
        int colI = c * 16 + m;
        int hh = colI >> 6, cq = colI & 63;
#pragma unroll
        for (int r = 0; r < 4; ++r) {
            int row = rowBase + wave * 16 + qd * 4 + r;
            if (row < n) Cout[((size_t)hh * NN + row) * 64 + cq] = f2b(acc[c][r]);
        }
    }
}

// ---------------- Aggregation + fused BN stats (half-split, per-sub nodes) --
// 8-lane subgroup <-> 128 B half-row (one full cache line); dynamic node
// ownership via LDS cursor; 256-node groups (R10 config — rate-optimal).

__global__ __launch_bounds__(256) void k_agg(
    const ushort* __restrict__ hwh, const int* __restrict__ rp,
    const uint* __restrict__ erec, const float* __restrict__ dinv,
    float* __restrict__ stats, ushort* __restrict__ aggb, int n) {
    __shared__ int cursor;
    __shared__ float lsum[64], lsq[64];
    int t = threadIdx.x;
    int lane = t & 63;
    int sl = lane & 7;       // lane within 8-lane sub
    int sub0 = lane & ~7;    // first lane of sub
    int half = blockIdx.x & 1;
    int nodeBase = (blockIdx.x >> 1) * 256;
    if (t == 0) cursor = 0;
    if (t < 64) { lsum[t] = 0.f; lsq[t] = 0.f; }
    __syncthreads();
    const uint4* hw4 = (const uint4*)hwh;  // half-planar: (half*NN + node)*8 + sl
    uint4* agg4 = (uint4*)aggb;            // interleaved: node*16 + half*8 + sl
    f32x2 ss[4], sq[4];
#pragma unroll
    for (int j = 0; j < 4; ++j) { ss[j] = (f32x2){0.f, 0.f}; sq[j] = (f32x2){0.f, 0.f}; }

    for (;;) {
        int ni = 0;
        if (sl == 0) ni = atomicAdd(&cursor, 1);
        ni = __shfl(ni, sub0);
        int node = nodeBase + ni;
        if (ni >= 256 || node >= n) break;
        float dn = dinv[node];
        f32x2 acc[4];
        {
            uint4 v = hw4[((size_t)half * NN + node) * 8 + sl];
            const uint* pv = (const uint*)&v;
#pragma unroll
            for (int j = 0; j < 4; ++j)
                acc[j] = (f32x2){dn * blo(pv[j]), dn * bhi(pv[j])};
        }
        int p = rp[node], pe = rp[node + 1];
        for (; p < pe; p += 4) {
            int i1 = p + 1 < pe ? p + 1 : pe - 1;
            int i2 = p + 2 < pe ? p + 2 : pe - 1;
            int i3 = p + 3 < pe ? p + 3 : pe - 1;
            uint r0 = erec[p], r1 = erec[i1], r2 = erec[i2], r3 = erec[i3];
            float w0 = __uint_as_float(r0 & 0xFFFE0000u);
            float w1 = (p + 1 < pe) ? __uint_as_float(r1 & 0xFFFE0000u) : 0.f;
            float w2 = (p + 2 < pe) ? __uint_as_float(r2 & 0xFFFE0000u) : 0.f;
            float w3 = (p + 3 < pe) ? __uint_as_float(r3 & 0xFFFE0000u) : 0.f;
            uint4 v0 = hw4[((size_t)half * NN + (r0 & 0x1FFFFu)) * 8 + sl];
            uint4 v1 = hw4[((size_t)half * NN + (r1 & 0x1FFFFu)) * 8 + sl];
            uint4 v2 = hw4[((size_t)half * NN + (r2 & 0x1FFFFu)) * 8 + sl];
            uint4 v3 = hw4[((size_t)half * NN + (r3 & 0x1FFFFu)) * 8 + sl];
            const uint* p0 = (const uint*)&v0;
            const uint* p1 = (const uint*)&v1;
            const uint* p2 = (const uint*)&v2;
            const uint* p3 = (const uint*)&v3;
            f32x2 wv0 = (f32x2){w0, w0}, wv1 = (f32x2){w1, w1};
            f32x2 wv2 = (f32x2){w2, w2}, wv3 = (f32x2){w3, w3};
#pragma unroll
            for (int j = 0; j < 4; ++j) {
                acc[j] = __builtin_elementwise_fma(wv0, (f32x2){blo(p0[j]), bhi(p0[j])}, acc[j]);
                acc[j] = __builtin_elementwise_fma(wv1, (f32x2){blo(p1[j]), bhi(p1[j])}, acc[j]);
                acc[j] = __builtin_elementwise_fma(wv2, (f32x2){blo(p2[j]), bhi(p2[j])}, acc[j]);
                acc[j] = __builtin_elementwise_fma(wv3, (f32x2){blo(p3[j]), bhi(p3[j])}, acc[j]);
            }
        }
        uint4 o;
        uint* po = (uint*)&o;
        f32x2 dn2 = (f32x2){dn, dn};
#pragma unroll
        for (int j = 0; j < 4; ++j) {
            f32x2 ov = dn2 * acc[j];
            ss[j] += ov;
            sq[j] = __builtin_elementwise_fma(ov, ov, sq[j]);
            po[j] = (uint)f2b(ov.x) | ((uint)f2b(ov.y) << 16);
        }
        agg4[(size_t)node * 16 + half * 8 + sl] = o;
    }
#pragma unroll
    for (int j = 0; j < 4; ++j) {
        atomicAdd(&lsum[sl * 8 + 2 * j], ss[j].x);
        atomicAdd(&lsum[sl * 8 + 2 * j + 1], ss[j].y);
        atomicAdd(&lsq[sl * 8 + 2 * j], sq[j].x);
        atomicAdd(&lsq[sl * 8 + 2 * j + 1], sq[j].y);
    }
    __syncthreads();
    if (t < 64) {
        atomicAdd(&stats[half * 64 + t], lsum[t]);
        atomicAdd(&stats[128 + half * 64 + t], lsq[t]);
    }
}

// ---------------- Pooling (BN+ReLU inline, vectorized) ----------------

__global__ void k_gbound(const int* __restrict__ batch, int* __restrict__ gptr, int n) {
    int g = blockIdx.x * 256 + threadIdx.x;
    if (g > GG) return;
    int lo = 0, hi = n;
    while (lo < hi) {
        int mid = (lo + hi) >> 1;
        if (batch[mid] < g) lo = mid + 1; else hi = mid;
    }
    gptr[g] = lo;
}

__global__ __launch_bounds__(256) void k_pool(
    const ushort* __restrict__ aggall, const float* __restrict__ statsall,
    const float* __restrict__ g1, const float* __restrict__ bt1,
    const float* __restrict__ gc, const float* __restrict__ btc,
    const int* __restrict__ gptr, float* __restrict__ pooled, float inv_n) {
    __shared__ float bsc[64], bshf[64];
    __shared__ float red[32][64];
    int g = blockIdx.x;
    int s = blockIdx.y;              // feature slice: 64 feats
    int sec = s >> 1;                // section (layer) 0..2
    int c = threadIdx.x & 7;         // uint4 chunk within slice
    int rg = threadIdx.x >> 3;       // row lane 0..31
    int t = threadIdx.x;

    if (t < 64) {
        int feat = (s & 1) * 64 + t;  // feature within section (0..127)
        const float* st = statsall + sec * 256;
        float mu = st[feat] * inv_n;
        float var = st[128 + feat] * inv_n - mu * mu;
        float gm = (sec == 0) ? g1[feat] : gc[(sec - 1) * H + feat];
        float bm = (sec == 0) ? bt1[feat] : btc[(sec - 1) * H + feat];
        float sc = gm * rsqrtf(var + EPSBN);
        bsc[t] = sc;
        bshf[t] = bm - mu * sc;
    }
    __syncthreads();

    int r0 = gptr[g], r1 = gptr[g + 1];
    const uint4* a4 = (const uint4*)aggall;
    size_t secBase = (size_t)sec * NN * 16;
    int cOff = (s & 1) * 8 + c;
    float acc[8];
#pragma unroll
    for (int j = 0; j < 8; ++j) acc[j] = 0.f;
    for (int r = r0 + rg; r < r1; r += 32) {
        uint4 v = a4[secBase + (size_t)r * 16 + cOff];
        const uint* pv = (const uint*)&v;
#pragma unroll
        for (int j = 0; j < 4; ++j) {
            int f0 = c * 8 + 2 * j;
            acc[2 * j]     += fmaxf(fmaf(blo(pv[j]), bsc[f0], bshf[f0]), 0.f);
            acc[2 * j + 1] += fmaxf(fmaf(bhi(pv[j]), bsc[f0 + 1], bshf[f0 + 1]), 0.f);
        }
    }
#pragma unroll
    for (int j = 0; j < 8; ++j) red[rg][c * 8 + j] = acc[j];
    __syncthreads();
    if (t < 64) {
        float sum = 0.f;
#pragma unroll
        for (int rr = 0; rr < 32; ++rr) sum += red[rr][t];
        float cnt = (float)(r1 - r0);
        pooled[g * LH + s * 64 + t] = sum / fmaxf(cnt, 1.f);
    }
}

// ---------------- MLP head ----------------

__global__ void k_mlp1(const float* __restrict__ pooled, const float* __restrict__ Wl1,
                       const float* __restrict__ bl1, float* __restrict__ z) {
    __shared__ float row[LH];
    int g = blockIdx.x;
    int j = threadIdx.x;  // 128 threads
    for (int k = j; k < LH; k += H) row[k] = pooled[g * LH + k];
    __syncthreads();
    float acc = bl1[j];
    for (int k = 0; k < LH; ++k) acc += row[k] * Wl1[k * H + j];
    z[g * H + j] = acc;
}

__global__ void k_zstats(const float* __restrict__ z, float* __restrict__ st) {
    int j = threadIdx.x;  // 128 threads, 1 block
    float s = 0.f, q = 0.f;
    for (int g = 0; g < GG; ++g) {
        float v = z[g * H + j];
        s += v;
        q += v * v;
    }
    st[j] = s;
    st[128 + j] = q;
}

__global__ void k_mlp2(const float* __restrict__ z, const float* __restrict__ st,
                       const float* __restrict__ gl, const float* __restrict__ btl,
                       const float* __restrict__ Wl2, const float* __restrict__ bl2,
                       float* __restrict__ out) {
    __shared__ float zn[H];
    __shared__ float logit[CC];
    int g = blockIdx.x;
    int t = threadIdx.x;  // 128 threads
    float mu = st[t] * (1.f / GG);
    float var = st[128 + t] * (1.f / GG) - mu * mu;
    float v = (z[g * H + t] - mu) * rsqrtf(var + EPSBN) * gl[t] + btl[t];
    zn[t] = fmaxf(v, 0.f);
    __syncthreads();
    if (t < CC) {
        float acc = bl2[t];
        for (int k = 0; k < H; ++k) acc += zn[k] * Wl2[k * CC + t];
        logit[t] = acc;
    }
    __syncthreads();
    if (t == 0) {
        float m = -1e30f;
        for (int c = 0; c < CC; ++c) m = fmaxf(m, logit[c]);
        float se = 0.f;
        for (int c = 0; c < CC; ++c) se += expf(logit[c] - m);
        float lse = m + logf(se);
        for (int c = 0; c < CC; ++c) out[g * CC + c] = logit[c] - lse;
    }
}

// ---------------- launch ----------------

extern "C" void kernel_launch(void* const* d_in, const int* in_sizes, int n_in,
                              void* d_out, int out_size, void* d_ws, size_t ws_size,
                              hipStream_t stream) {
    const float* x   = (const float*)d_in[0];
    const int*   ei  = (const int*)d_in[1];
    const int*   bat = (const int*)d_in[2];
    const float* W1  = (const float*)d_in[3];
    const float* g1  = (const float*)d_in[5];
    const float* bt1 = (const float*)d_in[6];
    const float* Wc  = (const float*)d_in[7];
    const float* gc  = (const float*)d_in[9];
    const float* btc = (const float*)d_in[10];
    const float* Wl1 = (const float*)d_in[11];
    const float* bl1 = (const float*)d_in[12];
    const float* gl  = (const float*)d_in[13];
    const float* btl = (const float*)d_in[14];
    const float* Wl2 = (const float*)d_in[15];
    const float* bl2 = (const float*)d_in[16];
    float* out = (float*)d_out;

    const int n = in_sizes[2];
    const int e = in_sizes[1] / 2;
    const int* src = ei;
    const int* dst = ei + e;
    const int nbuck = (n + 511) / 512;  // <= 256
    const float inv_n = 1.0f / (float)n;

    size_t off = 0;
    char* base = (char*)d_ws;
    auto take = [&](size_t nbytes) -> void* {
        void* p = base + off;
        off += (nbytes + 255) & ~(size_t)255;
        return p;
    };
    int*    rp      = (int*)take((size_t)(NN + 1) * 4);
    float*  dinv    = (float*)take((size_t)NN * 4);
    int*    bhist   = (int*)take(1024 + 8);
    int*    bbase   = (int*)take(1024 + 8);
    int*    bcursor = (int*)take(1024 + 8);
    uint*   ebuf    = (uint*)take((size_t)NE * 4);
    uint*   erec    = (uint*)take((size_t)NE * 4);
    float*  stats   = (float*)take(3 * 1024);
    int*    gptr    = (int*)take((size_t)(GG + 1) * 4);
    ushort* WTb     = (ushort*)take((size_t)3 * H * H * 2);
    ushort* hwb     = (ushort*)take((size_t)NN * H * 2);
    ushort* aggb    = (ushort*)take((size_t)3 * NN * H * 2);
    float*  pooled  = (float*)take((size_t)GG * LH * 4);
    float*  z       = (float*)take((size_t)GG * H * 4);
    float*  zst     = (float*)take(1024);

    // ---- weight transpose/convert ----
    k_wt<<<H, H, 0, stream>>>(W1, WTb, 1);
    k_wt<<<2 * H, H, 0, stream>>>(Wc, WTb + (size_t)H * H, 2);

    // ---- bucketed CSR build (erec written directly; no col buffer) ----
    hipMemsetAsync(bhist, 0, 1024 + 8, stream);
    k_bhist<<<256, 256, 0, stream>>>(dst, bhist, e, nbuck);
    k_bscan<<<1, 256, 0, stream>>>(bhist, bbase, bcursor, nbuck);
    k_bin<<<(e + 4095) / 4096, 256, 0, stream>>>(src, dst, bcursor, ebuf, e);
    k_bfinalA<<<nbuck, 256, 0, stream>>>(ebuf, bbase, rp, dinv, n, e);
    k_bfinalB<<<nbuck, 256, 0, stream>>>(ebuf, bbase, rp, dinv, erec, n);

    // ---- 3 GCN layers (BN+ReLU of layer l-1 fused into layer l's GEMM) ----
    hipMemsetAsync(stats, 0, 3 * 1024, stream);
    for (int l = 0; l < 3; ++l) {
        const ushort* WT = WTb + (size_t)l * H * H;

        if (l == 0) {
            k_gemm<0><<<(n + 63) / 64, 256, 0, stream>>>(
                x, WT, nullptr, nullptr, nullptr, inv_n, hwb, n);
        } else {
            const float* gm  = (l == 1) ? g1 : gc;
            const float* btm = (l == 1) ? bt1 : btc;
            k_gemm<1><<<(n + 63) / 64, 256, 0, stream>>>(
                aggb + (size_t)(l - 1) * NN * H, WT, stats + (size_t)(l - 1) * 256,
                gm, btm, inv_n, hwb, n);
        }
        k_agg<<<((n + 255) / 256) * 2, 256, 0, stream>>>(
            hwb, rp, erec, dinv, stats + (size_t)l * 256, aggb + (size_t)l * NN * H, n);
    }

    // ---- pooling ----
    k_gbound<<<3, 256, 0, stream>>>(bat, gptr, n);
    {
        dim3 pg(GG, 6);
        k_pool<<<pg, 256, 0, stream>>>(aggb, stats, g1, bt1, gc, btc, gptr, pooled, inv_n);
    }

    // ---- MLP head ----
    k_mlp1<<<GG, H, 0, stream>>>(pooled, Wl1, bl1, z);
    k_zstats<<<1, H, 0, stream>>>(z, zst);
    k_mlp2<<<GG, H, 0, stream>>>(z, zst, gl, btl, Wl2, bl2, out);
}